// Round 7
// baseline (67.593 us; speedup 1.0000x reference)
//
#include <hip/hip_runtime.h>

#define B_ 2
#define C_ 121
#define H_ 128
#define W_ 256
#define D_ 48
#define NT 256       // 4 waves: 64 w-quads x 4 d-groups
#define NDY 4        // disparities per thread
#define ZS 3         // d-split: 16 d per block
#define XROW 256
#define YROW 304     // 48 zero pad + 256 data
#define DEPTH 4      // per-wave channel ring depth

constexpr int HW = H_ * W_;

typedef float f32x4 __attribute__((ext_vector_type(4)));
typedef const void __attribute__((address_space(1)))* gas1_t;
typedef void __attribute__((address_space(3)))* las3_t;

// counted waits on OUR OWN vm ops; "memory" keeps mem ops ordered across,
// sched_barrier pins the scheduler (rule #18).
#define VMWAIT(NSTR) do { asm volatile("s_waitcnt vmcnt(" NSTR ")" ::: "memory"); \
                          __builtin_amdgcn_sched_barrier(0); } while (0)
#define LKWAIT()     do { asm volatile("s_waitcnt lgkmcnt(0)" ::: "memory"); \
                          __builtin_amdgcn_sched_barrier(0); } while (0)

__device__ __forceinline__ void stage_pair(const float* xrow, const float* yrow,
                                           float* xr, float* yr, int slot, int c)
{
    // global src is per-lane (xrow/yrow already include +wq*4); LDS dest is
    // wave-uniform base + lane*16 (global_load_lds semantics).
    __builtin_amdgcn_global_load_lds((gas1_t)(xrow + (size_t)c * HW),
                                     (las3_t)(xr + slot * XROW), 16, 0, 0);
    __builtin_amdgcn_global_load_lds((gas1_t)(yrow + (size_t)c * HW),
                                     (las3_t)(yr + slot * YROW + 48), 16, 0, 0);
}

template<int I>
__device__ __forceinline__ void chan(const float* xr, const float* yr,
                                     int w0, int bp, int d0, int b, int h, int ch,
                                     float (&acc)[NDY][4], float* __restrict__ out)
{
    const f32x4 xv = *(const f32x4*)(xr + I * XROW + w0);
    float yw[8];
    *(f32x4*)&yw[0] = *(const f32x4*)(yr + I * YROW + bp);
    *(f32x4*)&yw[4] = *(const f32x4*)(yr + I * YROW + bp + 4);

    const float xvv[4] = {xv.x, xv.y, xv.z, xv.w};
    #pragma unroll
    for (int jd = 0; jd < NDY; ++jd)
        #pragma unroll
        for (int jw = 0; jw < 4; ++jw)
            acc[jd][jw] += __builtin_fabsf(xvv[jw] - yw[4 + jw - jd]);

    // prefix boundaries c+1 = kk^2, kk=3..11; ch is wave-uniform -> SALU + uniform branch
    constexpr int KB[9] = {8, 15, 24, 35, 48, 63, 80, 99, 120};
    #pragma unroll
    for (int bi = 0; bi < 9; ++bi) {
        if (ch == KB[bi]) {
            const float inv = 1.0f / (float)(KB[bi] + 1);
            const size_t obase = (((size_t)b * 9 + bi) * D_) * (size_t)HW
                               + (size_t)h * W_ + (size_t)w0;
            #pragma unroll
            for (int jd = 0; jd < NDY; ++jd) {
                const int d = d0 + jd;
                f32x4 v;
                v.x = (w0 + 0 >= d) ? acc[jd][0] * inv : 0.0f;
                v.y = (w0 + 1 >= d) ? acc[jd][1] * inv : 0.0f;
                v.z = (w0 + 2 >= d) ? acc[jd][2] * inv : 0.0f;
                v.w = (w0 + 3 >= d) ? acc[jd][3] * inv : 0.0f;
                *(f32x4*)&out[obase + (size_t)d * HW] = v;
            }
        }
    }
}

__launch_bounds__(NT, 3)
__global__ void cost_volume_kernel(const float* __restrict__ xg,
                                   const float* __restrict__ yg,
                                   float* __restrict__ out)
{
    // per-wave-private rings: no inter-wave sharing, no barriers ever.
    __shared__ __align__(16) float XS[4][DEPTH][XROW];
    __shared__ __align__(16) float YS[4][DEPTH][YROW];

    const int t  = threadIdx.x;
    const int h  = blockIdx.x;
    const int b  = blockIdx.y;
    const int z  = blockIdx.z;          // owns d in [z*16, z*16+16)
    const int wq = t & 63;
    const int wv = t >> 6;
    const int d0 = z * 16 + wv * NDY;   // multiple of 4
    const int w0 = wq * 4;
    const int bp = w0 - d0 + 44;        // multiple of 4; window offsets [1,7]; bp+7 <= 303

    float* xr = &XS[wv][0][0];
    float* yr = &YS[wv][0][0];

    // zero the y left pads (p in [0,48)) of all ring slots — own-wave region.
    if (wq < 48) {
        yr[0 * YROW + wq] = 0.0f; yr[1 * YROW + wq] = 0.0f;
        yr[2 * YROW + wq] = 0.0f; yr[3 * YROW + wq] = 0.0f;
    }

    const size_t row0 = (((size_t)b * C_) * H_ + h) * (size_t)W_;
    const float* xrow = xg + row0 + (size_t)wq * 4;
    const float* yrow = yg + row0 + (size_t)wq * 4;

    float acc[NDY][4] = {};

    // prologue: channels 0..3 in flight (8 vm ops, issue order x0,y0,x1,y1,...)
    stage_pair(xrow, yrow, xr, yr, 0, 0);
    stage_pair(xrow, yrow, xr, yr, 1, 1);
    stage_pair(xrow, yrow, xr, yr, 2, 2);
    stage_pair(xrow, yrow, xr, yr, 3, 3);

    // steady state: wait vmcnt(6) -> channel c's pair complete (8 loads + any
    // store-acks outstanding; drain-oldest semantics make this exact).
    for (int g = 0; g < 29; ++g) {
        const int c0 = g * 4;
        VMWAIT("6"); chan<0>(xr, yr, w0, bp, d0, b, h, c0 + 0, acc, out);
        LKWAIT();    stage_pair(xrow, yrow, xr, yr, 0, c0 + 4);
        VMWAIT("6"); chan<1>(xr, yr, w0, bp, d0, b, h, c0 + 1, acc, out);
        LKWAIT();    stage_pair(xrow, yrow, xr, yr, 1, c0 + 5);
        VMWAIT("6"); chan<2>(xr, yr, w0, bp, d0, b, h, c0 + 2, acc, out);
        LKWAIT();    stage_pair(xrow, yrow, xr, yr, 2, c0 + 6);
        VMWAIT("6"); chan<3>(xr, yr, w0, bp, d0, b, h, c0 + 3, acc, out);
        LKWAIT();    stage_pair(xrow, yrow, xr, yr, 3, c0 + 7);
    }

    // g = 29: channels 116..119; only channel 120 still needs staging (slot 0).
    VMWAIT("6"); chan<0>(xr, yr, w0, bp, d0, b, h, 116, acc, out);
    LKWAIT();    stage_pair(xrow, yrow, xr, yr, 0, 120);
    VMWAIT("6"); chan<1>(xr, yr, w0, bp, d0, b, h, 117, acc, out);
    VMWAIT("4"); chan<2>(xr, yr, w0, bp, d0, b, h, 118, acc, out);
    VMWAIT("2"); chan<3>(xr, yr, w0, bp, d0, b, h, 119, acc, out);
    // tail: channel 120 (boundary kk=11)
    VMWAIT("0"); chan<0>(xr, yr, w0, bp, d0, b, h, 120, acc, out);
}

extern "C" void kernel_launch(void* const* d_in, const int* in_sizes, int n_in,
                              void* d_out, int out_size, void* d_ws, size_t ws_size,
                              hipStream_t stream)
{
    const float* x = (const float*)d_in[0];
    const float* y = (const float*)d_in[1];
    float* o = (float*)d_out;
    dim3 grid(H_, B_, ZS);   // z slowest: d-split siblings 256 ids apart -> same XCD
    dim3 block(NT, 1, 1);
    hipLaunchKernelGGL(cost_volume_kernel, grid, block, 0, stream, x, y, o);
}

// Round 8
// 52.796 us; speedup vs baseline: 1.2803x; 1.2803x over previous
//
#include <hip/hip_runtime.h>

#define B_ 2
#define C_ 121
#define H_ 128
#define W_ 256
#define D_ 48
#define CT 11        // channels per LDS chunk
#define NCHUNK 11    // 121 = 11 * 11
#define NT 256       // 4 waves: 64 w-quads x 4 d-groups
#define NDY 4        // disparities per thread
#define ZS 3         // d-split: 16 d per block
#define XROW 264     // 256 data + 8 pad -> 1056B stride (bank start rotates by 8)
#define YROW 312     // 48 zero-pad + 256 data + 8 pad -> 1248B stride (rotates 24)

constexpr int HW = H_ * W_;

typedef float f32x4 __attribute__((ext_vector_type(4)));
typedef const void __attribute__((address_space(1)))* gas1_t;
typedef void __attribute__((address_space(3)))* las3_t;

// counted wait on our OWN vm ops; "memory" clobber keeps memory ops ordered
#define VMWAIT(NSTR) asm volatile("s_waitcnt vmcnt(" NSTR ")" ::: "memory")
#define CFENCE()     asm volatile("" ::: "memory")

__launch_bounds__(NT, 3)
__global__ void cost_volume_kernel(const float* __restrict__ xg,
                                   const float* __restrict__ yg,
                                   float* __restrict__ out)
{
    // double-buffered cooperative tiles, shared by all 4 waves
    __shared__ __align__(16) float XLS[2][CT][XROW];
    __shared__ __align__(16) float YLS[2][CT][YROW];

    const int t  = threadIdx.x;
    const int h  = blockIdx.x;
    const int b  = blockIdx.y;
    const int z  = blockIdx.z;          // owns d in [z*16, z*16+16)
    const int wq = t & 63;              // w-quad: w = wq*4 .. wq*4+3
    const int wv = t >> 6;              // wave id = d-group, 0..3
    const int d0 = z * 16 + wv * NDY;   // multiple of 4
    const int w0 = wq * 4;
    const int bp = w0 - d0 + 44;        // multiple of 4; window idx [1,7]; bp+7 <= 303

    // zero the y left pads (p in [0,48)) of both buffers, once. (Values only
    // feed masked w<d outputs, but keep them defined.)
    for (int i = t; i < 2 * CT * 48; i += NT) {
        int nb = i / (CT * 48);
        int r  = i % (CT * 48);
        YLS[nb][r / 48][r % 48] = 0.0f;
    }

    const size_t row0 = (((size_t)b * C_) * H_ + h) * (size_t)W_;
    const float* xrow = xg + row0 + (size_t)wq * 4;
    const float* yrow = yg + row0 + (size_t)wq * 4;

    // cooperative stage: wave wv issues rows i === wv (mod 4) of 22 (11 x + 11 y)
    // -> fixed per-wave DMA counts: waves 0,1 -> 6; waves 2,3 -> 5.
    auto stage = [&](int chunk, int nb) {
        for (int i = wv; i < 2 * CT; i += 4) {
            const int cc = i >> 1;
            const size_t off = (size_t)(chunk * CT + cc) * HW;
            if (i & 1)
                __builtin_amdgcn_global_load_lds((gas1_t)(yrow + off),
                                                 (las3_t)&YLS[nb][cc][48], 16, 0, 0);
            else
                __builtin_amdgcn_global_load_lds((gas1_t)(xrow + off),
                                                 (las3_t)&XLS[nb][cc][0], 16, 0, 0);
        }
    };

    stage(0, 0);
    stage(1, 1);

    float acc[NDY][4] = {};

    for (int k = 0; k < NCHUNK; ++k) {
        const int cur = k & 1;

        // wait for OWN chunk-k DMAs only; chunk-k+1's stay in flight across
        // the barrier (counted-vmcnt pattern). Stores in the queue only make
        // this conservative (in-order retirement).
        if (k < NCHUNK - 1) {
            if (wv < 2) VMWAIT("6"); else VMWAIT("5");
        } else {
            VMWAIT("0");
        }
        __builtin_amdgcn_s_barrier();
        CFENCE();   // don't let ds_reads hoist above the barrier

        #pragma unroll
        for (int cc = 0; cc < CT; ++cc) {
            const f32x4 xv = *(const f32x4*)&XLS[cur][cc][w0];
            float yw[8];
            *(f32x4*)&yw[0] = *(const f32x4*)&YLS[cur][cc][bp];
            *(f32x4*)&yw[4] = *(const f32x4*)&YLS[cur][cc][bp + 4];

            const float xvv[4] = {xv.x, xv.y, xv.z, xv.w};
            #pragma unroll
            for (int jd = 0; jd < NDY; ++jd)
                #pragma unroll
                for (int jw = 0; jw < 4; ++jw)
                    acc[jd][jw] += __builtin_fabsf(xvv[jw] - yw[4 + jw - jd]);

            // prefix boundaries c+1 = kk^2, kk=3..11 (folds to scalar k==const)
            #pragma unroll
            for (int bi = 0; bi < 9; ++bi) {
                constexpr int KB[9] = {8, 15, 24, 35, 48, 63, 80, 99, 120};
                if (k * CT + cc == KB[bi]) {
                    const float inv = 1.0f / (float)(KB[bi] + 1);
                    const size_t obase = (((size_t)b * 9 + bi) * D_) * (size_t)HW
                                       + (size_t)h * W_ + (size_t)w0;
                    #pragma unroll
                    for (int jd = 0; jd < NDY; ++jd) {
                        const int d = d0 + jd;
                        f32x4 v;
                        v.x = (w0 + 0 >= d) ? acc[jd][0] * inv : 0.0f;
                        v.y = (w0 + 1 >= d) ? acc[jd][1] * inv : 0.0f;
                        v.z = (w0 + 2 >= d) ? acc[jd][2] * inv : 0.0f;
                        v.w = (w0 + 3 >= d) ? acc[jd][3] * inv : 0.0f;
                        *(f32x4*)&out[obase + (size_t)d * HW] = v;
                    }
                }
            }
        }

        // all waves done reading buf[cur] -> safe to restage it (chunk k+2)
        if (k + 2 < NCHUNK) {
            CFENCE();
            __builtin_amdgcn_s_barrier();
            stage(k + 2, cur);
        }
    }
}

extern "C" void kernel_launch(void* const* d_in, const int* in_sizes, int n_in,
                              void* d_out, int out_size, void* d_ws, size_t ws_size,
                              hipStream_t stream)
{
    const float* x = (const float*)d_in[0];
    const float* y = (const float*)d_in[1];
    float* o = (float*)d_out;
    dim3 grid(H_, B_, ZS);   // z slowest: d-split siblings 256 ids apart -> same XCD
    dim3 block(NT, 1, 1);
    hipLaunchKernelGGL(cost_volume_kernel, grid, block, 0, stream, x, y, o);
}